// Round 5
// baseline (1310.775 us; speedup 1.0000x reference)
//
#include <hip/hip_runtime.h>
#include <hip/hip_bf16.h>
#include <math.h>

// MLA prefill, bf16 MFMA, round 4 (resubmit): occupancy fixes (regs<=128 +
// split-K grids), attn T13 defer-max + T5 setprio.
// B=2 S=1024 H=4096 N=64 NOPE=128 ROPE=64 V=128 KV_LORA=512 Q_LORA=1536 QK=192

#define SCALE_QK 0.07216878364870322f  // 192^-0.5

typedef short bf16x8 __attribute__((ext_vector_type(8)));
typedef float f32x4  __attribute__((ext_vector_type(4)));

// ---------------------------------------------------------------------------
// cast fp32 -> bf16 (n % 8 == 0)
// ---------------------------------------------------------------------------
__global__ __launch_bounds__(256) void cast_f32_bf16(
    const float* __restrict__ src, __hip_bfloat16* __restrict__ dst, long n)
{
    long i = ((long)blockIdx.x * 256 + threadIdx.x) * 8;
    if (i >= n) return;
    float4 a = *(const float4*)(src + i);
    float4 b = *(const float4*)(src + i + 4);
    union { bf16x8 v; __hip_bfloat16 h[8]; } u;
    u.h[0] = __float2bfloat16(a.x); u.h[1] = __float2bfloat16(a.y);
    u.h[2] = __float2bfloat16(a.z); u.h[3] = __float2bfloat16(a.w);
    u.h[4] = __float2bfloat16(b.x); u.h[5] = __float2bfloat16(b.y);
    u.h[6] = __float2bfloat16(b.z); u.h[7] = __float2bfloat16(b.w);
    *(bf16x8*)(dst + i) = u.v;
}

// cast kv_a_w [576][4096] -> bf16 padded [640][4096], rows 576..639 = 0
__global__ __launch_bounds__(256) void cast_pad_kvaw(
    const float* __restrict__ src, __hip_bfloat16* __restrict__ dst)
{
    long i = ((long)blockIdx.x * 256 + threadIdx.x) * 8;
    if (i >= 640L * 4096) return;
    const int row = (int)(i >> 12);
    union { bf16x8 v; __hip_bfloat16 h[8]; } u;
    if (row < 576) {
        float4 a = *(const float4*)(src + i);
        float4 b = *(const float4*)(src + i + 4);
        u.h[0] = __float2bfloat16(a.x); u.h[1] = __float2bfloat16(a.y);
        u.h[2] = __float2bfloat16(a.z); u.h[3] = __float2bfloat16(a.w);
        u.h[4] = __float2bfloat16(b.x); u.h[5] = __float2bfloat16(b.y);
        u.h[6] = __float2bfloat16(b.z); u.h[7] = __float2bfloat16(b.w);
    } else {
        for (int j = 0; j < 8; ++j) u.h[j] = __float2bfloat16(0.f);
    }
    *(bf16x8*)(dst + i) = u.v;
}

// ---------------------------------------------------------------------------
// reduce: out[i] = sum_s parts[s*n + i]   (n % 4 == 0)
// ---------------------------------------------------------------------------
__global__ __launch_bounds__(256) void reduce_sum(
    const float* __restrict__ parts, float* __restrict__ out, long n, int S)
{
    long i = ((long)blockIdx.x * 256 + threadIdx.x) * 4;
    const long stride = (long)gridDim.x * 1024;
    for (; i < n; i += stride) {
        float4 acc = *(const float4*)(parts + i);
        for (int s = 1; s < S; ++s) {
            float4 v = *(const float4*)(parts + (size_t)s * n + i);
            acc.x += v.x; acc.y += v.y; acc.z += v.z; acc.w += v.w;
        }
        *(float4*)(out + i) = acc;
    }
}

// out[i] += a[i]   (n % 4 == 0)
__global__ __launch_bounds__(256) void add_inplace(
    float* __restrict__ out, const float* __restrict__ a, long n)
{
    long i = ((long)blockIdx.x * 256 + threadIdx.x) * 4;
    const long stride = (long)gridDim.x * 1024;
    for (; i < n; i += stride) {
        float4 o = *(const float4*)(out + i);
        float4 v = *(const float4*)(a + i);
        o.x += v.x; o.y += v.y; o.z += v.z; o.w += v.w;
        *(float4*)(out + i) = o;
    }
}

// ---------------------------------------------------------------------------
// GEMM bf16: C[M,N] (+)= A[M, z*K .. z*K+K] @ B[N, same]^T, MFMA 16x16x32.
// Tile 128x128, BK=32, 4 waves, fj-outer MFMA loop, __launch_bounds__(256,4)
// to force <=128 regs -> 16 waves/CU. Split-K via gridDim.z: z=0 writes C0,
// z>=1 writes Calt + (z-1)*M*N (always fp32 for split). lda/ldb = row strides.
// ---------------------------------------------------------------------------
template<int OUT_BF16>
__global__ __launch_bounds__(256, 4) void gemm_bf16(
    const __hip_bfloat16* __restrict__ A, const __hip_bfloat16* __restrict__ B,
    void* __restrict__ C0, float* __restrict__ Calt,
    int M, int N, int K, int lda, int ldb)
{
    __shared__ __hip_bfloat16 Asm[128 * 32];
    __shared__ __hip_bfloat16 Bsm[128 * 32];
    const int t  = threadIdx.x;
    const int w  = t >> 6, l = t & 63;
    const int wr = w >> 1, wc = w & 1;
    const int lr = l & 15, g = l >> 4;
    const int m0 = blockIdx.y * 128, n0 = blockIdx.x * 128;
    const int z  = blockIdx.z;
    const int srow = l >> 2;
    const int schk = l & 3;

    const __hip_bfloat16* Az = A + (size_t)z * K;
    const __hip_bfloat16* Bz = B + (size_t)z * K;

    f32x4 acc[4][4] = {};

    for (int k0 = 0; k0 < K; k0 += 32) {
#pragma unroll
        for (int i = 0; i < 2; ++i) {
            const int ia = w * 2 + i;
            const __hip_bfloat16* ga = Az + (size_t)(m0 + ia * 16 + srow) * lda + k0 + schk * 8;
            __builtin_amdgcn_global_load_lds(
                (const __attribute__((address_space(1))) void*)ga,
                (__attribute__((address_space(3))) void*)(Asm + ia * 512), 16, 0, 0);
            const __hip_bfloat16* gb = Bz + (size_t)(n0 + ia * 16 + srow) * ldb + k0 + schk * 8;
            __builtin_amdgcn_global_load_lds(
                (const __attribute__((address_space(1))) void*)gb,
                (__attribute__((address_space(3))) void*)(Bsm + ia * 512), 16, 0, 0);
        }
        __syncthreads();
        bf16x8 af[4];
#pragma unroll
        for (int fi = 0; fi < 4; ++fi)
            af[fi] = *(const bf16x8*)(Asm + (wr * 64 + fi * 16 + lr) * 32 + g * 8);
#pragma unroll
        for (int fj = 0; fj < 4; ++fj) {
            bf16x8 bfr = *(const bf16x8*)(Bsm + (wc * 64 + fj * 16 + lr) * 32 + g * 8);
#pragma unroll
            for (int fi = 0; fi < 4; ++fi)
                acc[fi][fj] = __builtin_amdgcn_mfma_f32_16x16x32_bf16(
                    af[fi], bfr, acc[fi][fj], 0, 0, 0);
        }
        __syncthreads();
    }

    // epilogue: D row = g*4 + r, col = lr
    if (OUT_BF16) {
        __hip_bfloat16* C = (__hip_bfloat16*)C0;
#pragma unroll
        for (int fi = 0; fi < 4; ++fi)
#pragma unroll
            for (int fj = 0; fj < 4; ++fj) {
                const int col = n0 + wc * 64 + fj * 16 + lr;
#pragma unroll
                for (int r = 0; r < 4; ++r) {
                    const size_t row = (size_t)(m0 + wr * 64 + fi * 16 + g * 4 + r);
                    C[row * N + col] = __float2bfloat16(acc[fi][fj][r]);
                }
            }
    } else {
        float* C = (z == 0) ? (float*)C0 : (Calt + (size_t)(z - 1) * M * N);
#pragma unroll
        for (int fi = 0; fi < 4; ++fi)
#pragma unroll
            for (int fj = 0; fj < 4; ++fj) {
                const int col = n0 + wc * 64 + fj * 16 + lr;
#pragma unroll
                for (int r = 0; r < 4; ++r) {
                    const size_t row = (size_t)(m0 + wr * 64 + fi * 16 + g * 4 + r);
                    C[row * N + col] = acc[fi][fj][r];
                }
            }
    }
}

// ---------------------------------------------------------------------------
// rmsnorm over rows of 1536 fp32 -> bf16 out
// ---------------------------------------------------------------------------
__global__ __launch_bounds__(256) void rmsnorm_qa(
    const float* __restrict__ x, const float* __restrict__ w,
    __hip_bfloat16* __restrict__ o)
{
    __shared__ float red[4];
    const int row = blockIdx.x;
    const float* xr = x + (size_t)row * 1536;
    float ss = 0.f;
#pragma unroll
    for (int i = threadIdx.x; i < 1536; i += 256) { float v = xr[i]; ss = fmaf(v, v, ss); }
#pragma unroll
    for (int off = 1; off < 64; off <<= 1) ss += __shfl_xor(ss, off, 64);
    const int lane = threadIdx.x & 63, wid = threadIdx.x >> 6;
    if (lane == 0) red[wid] = ss;
    __syncthreads();
    ss = red[0] + red[1] + red[2] + red[3];
    const float r = rsqrtf(ss / 1536.f + 1e-6f);
#pragma unroll
    for (int i = threadIdx.x; i < 1536; i += 256)
        o[(size_t)row * 1536 + i] = __float2bfloat16(xr[i] * r * w[i]);
}

// ---------------------------------------------------------------------------
// kv_a [2048][640] fp32 -> ckv bf16 [2048][512] (rmsnorm) + kpe bf16 (rope)
// ---------------------------------------------------------------------------
__global__ __launch_bounds__(256) void kv_norm_rope(
    const float* __restrict__ kva, const float* __restrict__ w,
    const int* __restrict__ pos, const float* __restrict__ cosT,
    const float* __restrict__ sinT, __hip_bfloat16* __restrict__ ckv,
    __hip_bfloat16* __restrict__ kpe)
{
    __shared__ float red[4];
    const int row = blockIdx.x;
    const float* xr = kva + (size_t)row * 640;
    float ss = 0.f;
#pragma unroll
    for (int i = threadIdx.x; i < 512; i += 256) { float v = xr[i]; ss = fmaf(v, v, ss); }
#pragma unroll
    for (int off = 1; off < 64; off <<= 1) ss += __shfl_xor(ss, off, 64);
    const int lane = threadIdx.x & 63, wid = threadIdx.x >> 6;
    if (lane == 0) red[wid] = ss;
    __syncthreads();
    ss = red[0] + red[1] + red[2] + red[3];
    const float r = rsqrtf(ss / 512.f + 1e-6f);
#pragma unroll
    for (int i = threadIdx.x; i < 512; i += 256)
        ckv[(size_t)row * 512 + i] = __float2bfloat16(xr[i] * r * w[i]);
    if (threadIdx.x < 64) {
        const int d = threadIdx.x;
        const int p = pos[row];
        const float xd = xr[512 + d];
        const float xp = xr[512 + (d ^ 32)];
        const float rot = (d < 32) ? -xp : xp;
        kpe[(size_t)row * 64 + d] = __float2bfloat16(xd * cosT[p * 64 + d] + rot * sinT[p * 64 + d]);
    }
}

// ---------------------------------------------------------------------------
// RoPE on q_pe in place, bf16. d and d^32 in same wave; loads precede store.
// ---------------------------------------------------------------------------
__global__ __launch_bounds__(256) void qpe_rope_bf(
    __hip_bfloat16* __restrict__ q, const int* __restrict__ pos,
    const float* __restrict__ cosT, const float* __restrict__ sinT)
{
    const int idx = blockIdx.x * 256 + threadIdx.x;
    const int d = idx & 63;
    const int n = (idx >> 6) & 63;
    const int row = idx >> 12;
    const int p = pos[row];
    __hip_bfloat16* qp = q + (size_t)row * 12288 + n * 192 + 128;
    const float xd = __bfloat162float(qp[d]);
    const float xp = __bfloat162float(qp[d ^ 32]);
    const float rot = (d < 32) ? -xp : xp;
    qp[d] = __float2bfloat16(xd * cosT[p * 64 + d] + rot * sinT[p * 64 + d]);
}

// ---------------------------------------------------------------------------
// Flash attention, bf16 MFMA. 4 waves, wave w owns q rows [w*16, w*16+16).
// T13 defer-max (THR=8), T5 setprio around MFMA clusters.
// ---------------------------------------------------------------------------
__global__ __launch_bounds__(256, 3) void attn_mfma(
    const __hip_bfloat16* __restrict__ q,     // [2048][12288]
    const __hip_bfloat16* __restrict__ kvup,  // [2048][16384] per-head K||V
    const __hip_bfloat16* __restrict__ kpe,   // [2048][64]
    __hip_bfloat16* __restrict__ attno)       // [2048][8192]
{
    __shared__ __hip_bfloat16 Ksm[64 * 200];
    __shared__ unsigned char  Vsm[128 * 144];
    __shared__ __hip_bfloat16 Psm[4 * 16 * 72];

    const int t  = threadIdx.x;
    const int w  = t >> 6, l = t & 63;
    const int lr = l & 15, g = l >> 4;
    const int qb = blockIdx.x, n = blockIdx.y, b = blockIdx.z;
    const int qs = qb * 64;
    const size_t rowQ = (size_t)b * 1024 + qs + w * 16 + lr;

    bf16x8 qf[6];
#pragma unroll
    for (int ks = 0; ks < 6; ++ks)
        qf[ks] = *(const bf16x8*)(q + rowQ * 12288 + n * 192 + ks * 32 + g * 8);

    f32x4 oacc[8] = {};
    float m_[4], l_[4];
#pragma unroll
    for (int r = 0; r < 4; ++r) { m_[r] = -INFINITY; l_[r] = 0.f; }

    __hip_bfloat16* Pw = Psm + w * 16 * 72;

    for (int kt = 0; kt <= qb; ++kt) {
        const int ct = kt * 64;
        // ---- stage K tile (64 x 192) ----
        {
            const int tr  = t & 63;
            const int chb = (t >> 6) * 6;
            const size_t grow = (size_t)b * 1024 + ct + tr;
#pragma unroll
            for (int i = 0; i < 6; ++i) {
                const int ch = chb + i;
                bf16x8 v;
                if (ch < 16) v = *(const bf16x8*)(kvup + grow * 16384 + n * 256 + ch * 8);
                else         v = *(const bf16x8*)(kpe + grow * 64 + (ch - 16) * 8);
                *(bf16x8*)(Ksm + tr * 200 + ch * 8) = v;
            }
        }
        // ---- stage V^T swizzled ----
        {
#pragma unroll
            for (int i = 0; i < 4; ++i) {
                const int cc  = t + 256 * i;
                const int tr  = cc >> 4;
                const int v0  = (cc & 15) * 8;
                const int key = cc & 7;
                const size_t grow = (size_t)b * 1024 + ct + tr;
                union { bf16x8 v; __hip_bfloat16 h[8]; } u;
                u.v = *(const bf16x8*)(kvup + grow * 16384 + n * 256 + 128 + v0);
                const int tb = (2 * tr) ^ (key << 4);
#pragma unroll
                for (int j = 0; j < 8; ++j)
                    *(__hip_bfloat16*)(Vsm + (size_t)(v0 + j) * 144 + tb) = u.h[j];
            }
        }
        __syncthreads();

        // ---- QK^T ----
        f32x4 sacc[4] = {};
        __builtin_amdgcn_s_setprio(1);
#pragma unroll
        for (int ks = 0; ks < 6; ++ks)
#pragma unroll
            for (int ft = 0; ft < 4; ++ft) {
                bf16x8 kf = *(const bf16x8*)(Ksm + (ft * 16 + lr) * 200 + ks * 32 + g * 8);
                sacc[ft] = __builtin_amdgcn_mfma_f32_16x16x32_bf16(qf[ks], kf, sacc[ft], 0, 0, 0);
            }
        __builtin_amdgcn_s_setprio(0);

        // ---- online softmax (defer-max THR=8) ----
        const bool diag = (kt == qb);
#pragma unroll
        for (int r = 0; r < 4; ++r) {
            const int qg = qs + w * 16 + g * 4 + r;
            float pv[4];
            float rmax = -3e38f;
#pragma unroll
            for (int ft = 0; ft < 4; ++ft) {
                float v = sacc[ft][r] * SCALE_QK;
                if (diag && (ct + ft * 16 + lr) > qg) v = -3e38f;
                pv[ft] = v;
                rmax = fmaxf(rmax, v);
            }
            rmax = fmaxf(rmax, __shfl_xor(rmax, 1, 64));
            rmax = fmaxf(rmax, __shfl_xor(rmax, 2, 64));
            rmax = fmaxf(rmax, __shfl_xor(rmax, 4, 64));
            rmax = fmaxf(rmax, __shfl_xor(rmax, 8, 64));
            if (!__all(rmax - m_[r] <= 8.f)) {
                const float mnew  = fmaxf(m_[r], rmax);
                const float alpha = __expf(m_[r] - mnew);
                m_[r] = mnew;
                l_[r] *= alpha;
#pragma unroll
                for (int fj = 0; fj < 8; ++fj) oacc[fj][r] *= alpha;
            }
            float ps = 0.f;
#pragma unroll
            for (int ft = 0; ft < 4; ++ft) {
                const float e = __expf(pv[ft] - m_[r]);
                pv[ft] = e;
                ps += e;
            }
            ps += __shfl_xor(ps, 1, 64);
            ps += __shfl_xor(ps, 2, 64);
            ps += __shfl_xor(ps, 4, 64);
            ps += __shfl_xor(ps, 8, 64);
            l_[r] += ps;
#pragma unroll
            for (int ft = 0; ft < 4; ++ft)
                Pw[(g * 4 + r) * 72 + ft * 16 + lr] = __float2bfloat16(pv[ft]);
        }

        // ---- PV ----
        __builtin_amdgcn_s_setprio(1);
#pragma unroll
        for (int s = 0; s < 2; ++s) {
            bf16x8 pa = *(const bf16x8*)(Pw + lr * 72 + s * 32 + g * 8);
#pragma unroll
            for (int fj = 0; fj < 8; ++fj) {
                const int v = fj * 16 + lr;
                const int chunk = (((4 * s + g) ^ ((v >> 3) & 7)) << 4);
                bf16x8 bv = *(const bf16x8*)(Vsm + (size_t)v * 144 + chunk);
                oacc[fj] = __builtin_amdgcn_mfma_f32_16x16x32_bf16(pa, bv, oacc[fj], 0, 0, 0);
            }
        }
        __builtin_amdgcn_s_setprio(0);
        __syncthreads();
    }

    // epilogue
#pragma unroll
    for (int r = 0; r < 4; ++r) {
        const float inv = 1.f / l_[r];
        const size_t orow = (size_t)b * 1024 + qs + w * 16 + g * 4 + r;
#pragma unroll
        for (int fj = 0; fj < 8; ++fj)
            attno[orow * 8192 + n * 128 + fj * 16 + lr] = __float2bfloat16(oacc[fj][r] * inv);
    }
}

// ---------------------------------------------------------------------------
extern "C" void kernel_launch(void* const* d_in, const int* in_sizes, int n_in,
                              void* d_out, int out_size, void* d_ws, size_t ws_size,
                              hipStream_t stream)
{
    const float* hidden    = (const float*)d_in[0];
    const int*   pos       = (const int*)d_in[1];
    const float* cosT      = (const float*)d_in[2];
    const float* sinT      = (const float*)d_in[3];
    const float* q_a_w     = (const float*)d_in[4];
    const float* q_a_ln_w  = (const float*)d_in[5];
    const float* q_b_w     = (const float*)d_in[6];
    const float* kv_a_w    = (const float*)d_in[7];
    const float* kv_a_ln_w = (const float*)d_in[8];
    const float* kv_b_w    = (const float*)d_in[9];
    const float* o_w       = (const float*)d_in[10];
    float* out = (float*)d_out;

    char* p = (char*)d_ws;
    __hip_bfloat16* hbf      = (__hip_bfloat16*)p; p += 2048L * 4096 * 2;   // 16.8 MB
    __hip_bfloat16* wbf      = (__hip_bfloat16*)p; p += 67108864;           // 67.1 MB
    float*          parts    = (float*)p;          p += 2048L * 1536 * 4 * 4; // 50.3 MB arena
    float*          qa_f32   = (float*)p;          p += 2048L * 1536 * 4;
    __hip_bfloat16* qa_bf    = (__hip_bfloat16*)p; p += 2048L * 1536 * 2;
    __hip_bfloat16* qbuf_bf  = (__hip_bfloat16*)p; p += 2048L * 12288 * 2;
    float*          kva_f32  = (float*)p;          p += 2048L * 640 * 4;
    __hip_bfloat16* ckv_bf   = (__hip_bfloat16*)p; p += 2048L * 512 * 2;
    __hip_bfloat16* kpe_bf   = (__hip_bfloat16*)p; p += 2048L * 64 * 2;
    __hip_bfloat16* kvup_bf  = (__hip_bfloat16*)p; p += 2048L * 16384 * 2;
    __hip_bfloat16* attno_bf = (__hip_bfloat16*)p; p += 2048L * 8192 * 2;
    // total ~312 MB

    auto nb8 = [](long n) { return (int)((n / 8 + 255) / 256); };

    // hidden -> bf16
    cast_f32_bf16<<<nb8(2048L * 4096), 256, 0, stream>>>(hidden, hbf, 2048L * 4096);

    // q_a = hidden @ q_a_w^T, split-K=4 (grid 768 blocks), fp32 partials
    cast_f32_bf16<<<nb8(1536L * 4096), 256, 0, stream>>>(q_a_w, wbf, 1536L * 4096);
    gemm_bf16<0><<<dim3(12, 16, 4), 256, 0, stream>>>(hbf, wbf, parts, parts + 2048L * 1536,
                                                      2048, 1536, 1024, 4096, 4096);
    reduce_sum<<<2048, 256, 0, stream>>>(parts, qa_f32, 2048L * 1536, 4);
    rmsnorm_qa<<<2048, 256, 0, stream>>>(qa_f32, q_a_ln_w, qa_bf);

    // kv_a = hidden @ kv_a_w^T (N padded 640), split-K=8 (grid 640 blocks)
    cast_pad_kvaw<<<nb8(640L * 4096), 256, 0, stream>>>(kv_a_w, wbf);
    gemm_bf16<0><<<dim3(5, 16, 8), 256, 0, stream>>>(hbf, wbf, parts, parts + 2048L * 640,
                                                     2048, 640, 512, 4096, 4096);
    reduce_sum<<<1280, 256, 0, stream>>>(parts, kva_f32, 2048L * 640, 8);
    kv_norm_rope<<<2048, 256, 0, stream>>>(kva_f32, kv_a_ln_w, pos, cosT, sinT, ckv_bf, kpe_bf);

    // q = rms(q_a) @ q_b_w^T (bf16 out, grid 1536 blocks)
    cast_f32_bf16<<<nb8(12288L * 1536), 256, 0, stream>>>(q_b_w, wbf, 12288L * 1536);
    gemm_bf16<1><<<dim3(96, 16, 1), 256, 0, stream>>>(qa_bf, wbf, qbuf_bf, nullptr,
                                                      2048, 12288, 1536, 1536, 1536);
    qpe_rope_bf<<<32768, 256, 0, stream>>>(qbuf_bf, pos, cosT, sinT);

    // kvup = ckv @ kv_b_w^T (bf16 out, grid 2048 blocks)
    cast_f32_bf16<<<nb8(16384L * 512), 256, 0, stream>>>(kv_b_w, wbf, 16384L * 512);
    gemm_bf16<1><<<dim3(128, 16, 1), 256, 0, stream>>>(ckv_bf, wbf, kvup_bf, nullptr,
                                                       2048, 16384, 512, 512, 512);

    // flash attention
    attn_mfma<<<dim3(16, 64, 2), 256, 0, stream>>>(qbuf_bf, kvup_bf, kpe_bf, attno_bf);

    // out = attno @ o_w^T, split-K=2 (grid 1024 blocks): z0 -> out, z1 -> parts
    cast_f32_bf16<<<nb8(4096L * 8192), 256, 0, stream>>>(o_w, wbf, 4096L * 8192);
    gemm_bf16<0><<<dim3(32, 16, 2), 256, 0, stream>>>(attno_bf, wbf, out, parts,
                                                      2048, 4096, 4096, 8192, 8192);
    add_inplace<<<2048, 256, 0, stream>>>(out, parts, 2048L * 4096);
}

// Round 7
// 987.051 us; speedup vs baseline: 1.3280x; 1.3280x over previous
//
#include <hip/hip_runtime.h>
#include <hip/hip_bf16.h>
#include <math.h>

// MLA prefill, bf16 MFMA, round 6 (resubmit): round-4 GEMM occupancy fixes;
// attention reverted to round-3 structure, widened to TQ=128 (8 waves) with
// fully-masked-wave skip.
// B=2 S=1024 H=4096 N=64 NOPE=128 ROPE=64 V=128 KV_LORA=512 Q_LORA=1536 QK=192

#define SCALE_QK 0.07216878364870322f  // 192^-0.5

typedef short bf16x8 __attribute__((ext_vector_type(8)));
typedef float f32x4  __attribute__((ext_vector_type(4)));

// ---------------------------------------------------------------------------
// cast fp32 -> bf16 (n % 8 == 0)
// ---------------------------------------------------------------------------
__global__ __launch_bounds__(256) void cast_f32_bf16(
    const float* __restrict__ src, __hip_bfloat16* __restrict__ dst, long n)
{
    long i = ((long)blockIdx.x * 256 + threadIdx.x) * 8;
    if (i >= n) return;
    float4 a = *(const float4*)(src + i);
    float4 b = *(const float4*)(src + i + 4);
    union { bf16x8 v; __hip_bfloat16 h[8]; } u;
    u.h[0] = __float2bfloat16(a.x); u.h[1] = __float2bfloat16(a.y);
    u.h[2] = __float2bfloat16(a.z); u.h[3] = __float2bfloat16(a.w);
    u.h[4] = __float2bfloat16(b.x); u.h[5] = __float2bfloat16(b.y);
    u.h[6] = __float2bfloat16(b.z); u.h[7] = __float2bfloat16(b.w);
    *(bf16x8*)(dst + i) = u.v;
}

// cast kv_a_w [576][4096] -> bf16 padded [640][4096], rows 576..639 = 0
__global__ __launch_bounds__(256) void cast_pad_kvaw(
    const float* __restrict__ src, __hip_bfloat16* __restrict__ dst)
{
    long i = ((long)blockIdx.x * 256 + threadIdx.x) * 8;
    if (i >= 640L * 4096) return;
    const int row = (int)(i >> 12);
    union { bf16x8 v; __hip_bfloat16 h[8]; } u;
    if (row < 576) {
        float4 a = *(const float4*)(src + i);
        float4 b = *(const float4*)(src + i + 4);
        u.h[0] = __float2bfloat16(a.x); u.h[1] = __float2bfloat16(a.y);
        u.h[2] = __float2bfloat16(a.z); u.h[3] = __float2bfloat16(a.w);
        u.h[4] = __float2bfloat16(b.x); u.h[5] = __float2bfloat16(b.y);
        u.h[6] = __float2bfloat16(b.z); u.h[7] = __float2bfloat16(b.w);
    } else {
        for (int j = 0; j < 8; ++j) u.h[j] = __float2bfloat16(0.f);
    }
    *(bf16x8*)(dst + i) = u.v;
}

// ---------------------------------------------------------------------------
// reduce: out[i] = sum_s parts[s*n + i]   (n % 4 == 0)
// ---------------------------------------------------------------------------
__global__ __launch_bounds__(256) void reduce_sum(
    const float* __restrict__ parts, float* __restrict__ out, long n, int S)
{
    long i = ((long)blockIdx.x * 256 + threadIdx.x) * 4;
    const long stride = (long)gridDim.x * 1024;
    for (; i < n; i += stride) {
        float4 acc = *(const float4*)(parts + i);
        for (int s = 1; s < S; ++s) {
            float4 v = *(const float4*)(parts + (size_t)s * n + i);
            acc.x += v.x; acc.y += v.y; acc.z += v.z; acc.w += v.w;
        }
        *(float4*)(out + i) = acc;
    }
}

// out[i] += a[i]   (n % 4 == 0)
__global__ __launch_bounds__(256) void add_inplace(
    float* __restrict__ out, const float* __restrict__ a, long n)
{
    long i = ((long)blockIdx.x * 256 + threadIdx.x) * 4;
    const long stride = (long)gridDim.x * 1024;
    for (; i < n; i += stride) {
        float4 o = *(const float4*)(out + i);
        float4 v = *(const float4*)(a + i);
        o.x += v.x; o.y += v.y; o.z += v.z; o.w += v.w;
        *(float4*)(out + i) = o;
    }
}

// ---------------------------------------------------------------------------
// GEMM bf16: C[M,N] (+)= A[M, z*K .. z*K+K] @ B[N, same]^T, MFMA 16x16x32.
// Tile 128x128, BK=32, 4 waves, fj-outer, __launch_bounds__(256,4).
// Split-K via gridDim.z: z=0 -> C0, z>=1 -> Calt + (z-1)*M*N (fp32).
// ---------------------------------------------------------------------------
template<int OUT_BF16>
__global__ __launch_bounds__(256, 4) void gemm_bf16(
    const __hip_bfloat16* __restrict__ A, const __hip_bfloat16* __restrict__ B,
    void* __restrict__ C0, float* __restrict__ Calt,
    int M, int N, int K, int lda, int ldb)
{
    __shared__ __hip_bfloat16 Asm[128 * 32];
    __shared__ __hip_bfloat16 Bsm[128 * 32];
    const int t  = threadIdx.x;
    const int w  = t >> 6, l = t & 63;
    const int wr = w >> 1, wc = w & 1;
    const int lr = l & 15, g = l >> 4;
    const int m0 = blockIdx.y * 128, n0 = blockIdx.x * 128;
    const int z  = blockIdx.z;
    const int srow = l >> 2;
    const int schk = l & 3;

    const __hip_bfloat16* Az = A + (size_t)z * K;
    const __hip_bfloat16* Bz = B + (size_t)z * K;

    f32x4 acc[4][4] = {};

    for (int k0 = 0; k0 < K; k0 += 32) {
#pragma unroll
        for (int i = 0; i < 2; ++i) {
            const int ia = w * 2 + i;
            const __hip_bfloat16* ga = Az + (size_t)(m0 + ia * 16 + srow) * lda + k0 + schk * 8;
            __builtin_amdgcn_global_load_lds(
                (const __attribute__((address_space(1))) void*)ga,
                (__attribute__((address_space(3))) void*)(Asm + ia * 512), 16, 0, 0);
            const __hip_bfloat16* gb = Bz + (size_t)(n0 + ia * 16 + srow) * ldb + k0 + schk * 8;
            __builtin_amdgcn_global_load_lds(
                (const __attribute__((address_space(1))) void*)gb,
                (__attribute__((address_space(3))) void*)(Bsm + ia * 512), 16, 0, 0);
        }
        __syncthreads();
        bf16x8 af[4];
#pragma unroll
        for (int fi = 0; fi < 4; ++fi)
            af[fi] = *(const bf16x8*)(Asm + (wr * 64 + fi * 16 + lr) * 32 + g * 8);
#pragma unroll
        for (int fj = 0; fj < 4; ++fj) {
            bf16x8 bfr = *(const bf16x8*)(Bsm + (wc * 64 + fj * 16 + lr) * 32 + g * 8);
#pragma unroll
            for (int fi = 0; fi < 4; ++fi)
                acc[fi][fj] = __builtin_amdgcn_mfma_f32_16x16x32_bf16(
                    af[fi], bfr, acc[fi][fj], 0, 0, 0);
        }
        __syncthreads();
    }

    // epilogue: D row = g*4 + r, col = lr
    if (OUT_BF16) {
        __hip_bfloat16* C = (__hip_bfloat16*)C0;
#pragma unroll
        for (int fi = 0; fi < 4; ++fi)
#pragma unroll
            for (int fj = 0; fj < 4; ++fj) {
                const int col = n0 + wc * 64 + fj * 16 + lr;
#pragma unroll
                for (int r = 0; r < 4; ++r) {
                    const size_t row = (size_t)(m0 + wr * 64 + fi * 16 + g * 4 + r);
                    C[row * N + col] = __float2bfloat16(acc[fi][fj][r]);
                }
            }
    } else {
        float* C = (z == 0) ? (float*)C0 : (Calt + (size_t)(z - 1) * M * N);
#pragma unroll
        for (int fi = 0; fi < 4; ++fi)
#pragma unroll
            for (int fj = 0; fj < 4; ++fj) {
                const int col = n0 + wc * 64 + fj * 16 + lr;
#pragma unroll
                for (int r = 0; r < 4; ++r) {
                    const size_t row = (size_t)(m0 + wr * 64 + fi * 16 + g * 4 + r);
                    C[row * N + col] = acc[fi][fj][r];
                }
            }
    }
}

// ---------------------------------------------------------------------------
// rmsnorm over rows of 1536 fp32 -> bf16 out
// ---------------------------------------------------------------------------
__global__ __launch_bounds__(256) void rmsnorm_qa(
    const float* __restrict__ x, const float* __restrict__ w,
    __hip_bfloat16* __restrict__ o)
{
    __shared__ float red[4];
    const int row = blockIdx.x;
    const float* xr = x + (size_t)row * 1536;
    float ss = 0.f;
#pragma unroll
    for (int i = threadIdx.x; i < 1536; i += 256) { float v = xr[i]; ss = fmaf(v, v, ss); }
#pragma unroll
    for (int off = 1; off < 64; off <<= 1) ss += __shfl_xor(ss, off, 64);
    const int lane = threadIdx.x & 63, wid = threadIdx.x >> 6;
    if (lane == 0) red[wid] = ss;
    __syncthreads();
    ss = red[0] + red[1] + red[2] + red[3];
    const float r = rsqrtf(ss / 1536.f + 1e-6f);
#pragma unroll
    for (int i = threadIdx.x; i < 1536; i += 256)
        o[(size_t)row * 1536 + i] = __float2bfloat16(xr[i] * r * w[i]);
}

// ---------------------------------------------------------------------------
// kv_a [2048][640] fp32 -> ckv bf16 [2048][512] (rmsnorm) + kpe bf16 (rope)
// ---------------------------------------------------------------------------
__global__ __launch_bounds__(256) void kv_norm_rope(
    const float* __restrict__ kva, const float* __restrict__ w,
    const int* __restrict__ pos, const float* __restrict__ cosT,
    const float* __restrict__ sinT, __hip_bfloat16* __restrict__ ckv,
    __hip_bfloat16* __restrict__ kpe)
{
    __shared__ float red[4];
    const int row = blockIdx.x;
    const float* xr = kva + (size_t)row * 640;
    float ss = 0.f;
#pragma unroll
    for (int i = threadIdx.x; i < 512; i += 256) { float v = xr[i]; ss = fmaf(v, v, ss); }
#pragma unroll
    for (int off = 1; off < 64; off <<= 1) ss += __shfl_xor(ss, off, 64);
    const int lane = threadIdx.x & 63, wid = threadIdx.x >> 6;
    if (lane == 0) red[wid] = ss;
    __syncthreads();
    ss = red[0] + red[1] + red[2] + red[3];
    const float r = rsqrtf(ss / 512.f + 1e-6f);
#pragma unroll
    for (int i = threadIdx.x; i < 512; i += 256)
        ckv[(size_t)row * 512 + i] = __float2bfloat16(xr[i] * r * w[i]);
    if (threadIdx.x < 64) {
        const int d = threadIdx.x;
        const int p = pos[row];
        const float xd = xr[512 + d];
        const float xp = xr[512 + (d ^ 32)];
        const float rot = (d < 32) ? -xp : xp;
        kpe[(size_t)row * 64 + d] = __float2bfloat16(xd * cosT[p * 64 + d] + rot * sinT[p * 64 + d]);
    }
}

// ---------------------------------------------------------------------------
// RoPE on q_pe in place, bf16. d and d^32 in same wave; loads precede store.
// ---------------------------------------------------------------------------
__global__ __launch_bounds__(256) void qpe_rope_bf(
    __hip_bfloat16* __restrict__ q, const int* __restrict__ pos,
    const float* __restrict__ cosT, const float* __restrict__ sinT)
{
    const int idx = blockIdx.x * 256 + threadIdx.x;
    const int d = idx & 63;
    const int n = (idx >> 6) & 63;
    const int row = idx >> 12;
    const int p = pos[row];
    __hip_bfloat16* qp = q + (size_t)row * 12288 + n * 192 + 128;
    const float xd = __bfloat162float(qp[d]);
    const float xp = __bfloat162float(qp[d ^ 32]);
    const float rot = (d < 32) ? -xp : xp;
    qp[d] = __float2bfloat16(xd * cosT[p * 64 + d] + rot * sinT[p * 64 + d]);
}

// ---------------------------------------------------------------------------
// Flash attention, bf16 MFMA, TQ=128 (8 waves, 512 thr), TK=64.
// Block = (qb 0..7, head n, batch b). Wave w owns q rows qs + [w*16, w*16+16).
// Per kt: stage K(64x192, stride 200) + V^T(swizzled); waves with fully-masked
// tiles skip compute (barriers outside the branch). Round-3 softmax (no
// setprio / no defer-max / no launch_bounds min-waves).
// LDS: K 25600 + V^T 18432 + P 18432 = 62464 B.
// ---------------------------------------------------------------------------
__global__ __launch_bounds__(512) void attn_mfma(
    const __hip_bfloat16* __restrict__ q,     // [2048][12288]
    const __hip_bfloat16* __restrict__ kvup,  // [2048][16384] per-head K||V
    const __hip_bfloat16* __restrict__ kpe,   // [2048][64]
    __hip_bfloat16* __restrict__ attno)       // [2048][8192]
{
    __shared__ __hip_bfloat16 Ksm[64 * 200];
    __shared__ unsigned char  Vsm[128 * 144];
    __shared__ __hip_bfloat16 Psm[8 * 16 * 72];

    const int t  = threadIdx.x;
    const int w  = t >> 6, l = t & 63;
    const int lr = l & 15, g = l >> 4;
    const int qb = blockIdx.x, n = blockIdx.y, b = blockIdx.z;
    const int qs = qb * 128;
    const size_t rowQ = (size_t)b * 1024 + qs + w * 16 + lr;

    bf16x8 qf[6];
#pragma unroll
    for (int ks = 0; ks < 6; ++ks)
        qf[ks] = *(const bf16x8*)(q + rowQ * 12288 + n * 192 + ks * 32 + g * 8);

    f32x4 oacc[8] = {};
    float m_[4], l_[4];
#pragma unroll
    for (int r = 0; r < 4; ++r) { m_[r] = -INFINITY; l_[r] = 0.f; }

    __hip_bfloat16* Pw = Psm + w * 16 * 72;
    const int wave_qmax = qs + w * 16 + 15;
    const int ktmax = 2 * qb + 1;

    for (int kt = 0; kt <= ktmax; ++kt) {
        const int ct = kt * 64;
        // ---- stage K tile (64 rows x 24 chunks of 8): row = t>>3, ci = t&7 ----
        {
            const int tr = t >> 3;
            const int ci = t & 7;
            const size_t grow = (size_t)b * 1024 + ct + tr;
            bf16x8 v0 = *(const bf16x8*)(kvup + grow * 16384 + n * 256 + ci * 8);
            bf16x8 v1 = *(const bf16x8*)(kvup + grow * 16384 + n * 256 + (ci + 8) * 8);
            bf16x8 v2 = *(const bf16x8*)(kpe + grow * 64 + ci * 8);
            *(bf16x8*)(Ksm + tr * 200 + ci * 8) = v0;
            *(bf16x8*)(Ksm + tr * 200 + (ci + 8) * 8) = v1;
            *(bf16x8*)(Ksm + tr * 200 + (ci + 16) * 8) = v2;
        }
        // ---- stage V^T swizzled: 1024 chunk-loads, 2 per thread ----
        {
#pragma unroll
            for (int i = 0; i < 2; ++i) {
                const int cc  = t + 512 * i;
                const int tr  = cc >> 4;
                const int v0  = (cc & 15) * 8;
                const int key = cc & 7;
                const size_t grow = (size_t)b * 1024 + ct + tr;
                union { bf16x8 v; __hip_bfloat16 h[8]; } u;
                u.v = *(const bf16x8*)(kvup + grow * 16384 + n * 256 + 128 + v0);
                const int tb = (2 * tr) ^ (key << 4);
#pragma unroll
                for (int j = 0; j < 8; ++j)
                    *(__hip_bfloat16*)(Vsm + (size_t)(v0 + j) * 144 + tb) = u.h[j];
            }
        }
        __syncthreads();

        const bool active = (ct <= wave_qmax);
        if (active) {
            // ---- QK^T: D row(q) = g*4+r, col(t) = ft*16+lr ----
            f32x4 sacc[4] = {};
#pragma unroll
            for (int ks = 0; ks < 6; ++ks)
#pragma unroll
                for (int ft = 0; ft < 4; ++ft) {
                    bf16x8 kf = *(const bf16x8*)(Ksm + (ft * 16 + lr) * 200 + ks * 32 + g * 8);
                    sacc[ft] = __builtin_amdgcn_mfma_f32_16x16x32_bf16(qf[ks], kf, sacc[ft], 0, 0, 0);
                }

            // ---- online softmax (vanilla, round-3 form) ----
            const bool diag = (kt >= 2 * qb);   // only last two tiles need masking
#pragma unroll
            for (int r = 0; r < 4; ++r) {
                const int qg = qs + w * 16 + g * 4 + r;
                float pv[4];
                float rmax = -3e38f;
#pragma unroll
                for (int ft = 0; ft < 4; ++ft) {
                    float v = sacc[ft][r] * SCALE_QK;
                    if (diag && (ct + ft * 16 + lr) > qg) v = -3e38f;
                    pv[ft] = v;
                    rmax = fmaxf(rmax, v);
                }
                rmax = fmaxf(rmax, __shfl_xor(rmax, 1, 64));
                rmax = fmaxf(rmax, __shfl_xor(rmax, 2, 64));
                rmax = fmaxf(rmax, __shfl_xor(rmax, 4, 64));
                rmax = fmaxf(rmax, __shfl_xor(rmax, 8, 64));
                const float mnew  = fmaxf(m_[r], rmax);
                const float alpha = __expf(m_[r] - mnew);
                m_[r] = mnew;
                float ps = 0.f;
#pragma unroll
                for (int ft = 0; ft < 4; ++ft) {
                    const float e = __expf(pv[ft] - mnew);
                    pv[ft] = e;
                    ps += e;
                }
                ps += __shfl_xor(ps, 1, 64);
                ps += __shfl_xor(ps, 2, 64);
                ps += __shfl_xor(ps, 4, 64);
                ps += __shfl_xor(ps, 8, 64);
                l_[r] = l_[r] * alpha + ps;
#pragma unroll
                for (int fj = 0; fj < 8; ++fj) oacc[fj][r] *= alpha;
#pragma unroll
                for (int ft = 0; ft < 4; ++ft)
                    Pw[(g * 4 + r) * 72 + ft * 16 + lr] = __float2bfloat16(pv[ft]);
            }

            // ---- PV: A = P (row=lr, k contiguous), B = V^T frags ----
#pragma unroll
            for (int s = 0; s < 2; ++s) {
                bf16x8 pa = *(const bf16x8*)(Pw + lr * 72 + s * 32 + g * 8);
#pragma unroll
                for (int fj = 0; fj < 8; ++fj) {
                    const int v = fj * 16 + lr;
                    const int chunk = (((4 * s + g) ^ ((v >> 3) & 7)) << 4);
                    bf16x8 bv = *(const bf16x8*)(Vsm + (size_t)v * 144 + chunk);
                    oacc[fj] = __builtin_amdgcn_mfma_f32_16x16x32_bf16(pa, bv, oacc[fj], 0, 0, 0);
                }
            }
        }
        __syncthreads();
    }

    // epilogue
#pragma unroll
    for (int r = 0; r < 4; ++r) {
        const float inv = 1.f / l_[r];
        const size_t orow = (size_t)b * 1024 + qs + w * 16 + g * 4 + r;
#pragma unroll
        for (int fj = 0; fj < 8; ++fj)
            attno[orow * 8192 + n * 128 + fj * 16 + lr] = __float2bfloat16(oacc[fj][r] * inv);
    }
}

// ---------------------------------------------------------------------------
extern "C" void kernel_launch(void* const* d_in, const int* in_sizes, int n_in,
                              void* d_out, int out_size, void* d_ws, size_t ws_size,
                              hipStream_t stream)
{
    const float* hidden    = (const float*)d_in[0];
    const int*   pos       = (const int*)d_in[1];
    const float* cosT      = (const float*)d_in[2];
    const float* sinT      = (const float*)d_in[3];
    const float* q_a_w     = (const float*)d_in[4];
    const float* q_a_ln_w  = (const float*)d_in[5];
    const float* q_b_w     = (const float*)d_in[6];
    const float* kv_a_w    = (const float*)d_in[7];
    const float* kv_a_ln_w = (const float*)d_in[8];
    const float* kv_b_w    = (const float*)d_in[9];
    const float* o_w       = (const float*)d_in[10];
    float* out = (float*)d_out;

    char* p = (char*)d_ws;
    __hip_bfloat16* hbf      = (__hip_bfloat16*)p; p += 2048L * 4096 * 2;   // 16.8 MB
    __hip_bfloat16* wbf      = (__hip_bfloat16*)p; p += 67108864;           // 67.1 MB
    float*          parts    = (float*)p;          p += 2048L * 1536 * 4 * 4; // 50.3 MB arena
    float*          qa_f32   = (float*)p;          p += 2048L * 1536 * 4;
    __hip_bfloat16* qa_bf    = (__hip_bfloat16*)p; p += 2048L * 1536 * 2;
    __hip_bfloat16* qbuf_bf  = (__hip_bfloat16*)p; p += 2048L * 12288 * 2;
    float*          kva_f32  = (float*)p;          p += 2048L * 640 * 4;
    __hip_bfloat16* ckv_bf   = (__hip_bfloat16*)p; p += 2048L * 512 * 2;
    __hip_bfloat16* kpe_bf   = (__hip_bfloat16*)p; p += 2048L * 64 * 2;
    __hip_bfloat16* kvup_bf  = (__hip_bfloat16*)p; p += 2048L * 16384 * 2;
    __hip_bfloat16* attno_bf = (__hip_bfloat16*)p; p += 2048L * 8192 * 2;
    // total ~312 MB

    auto nb8 = [](long n) { return (int)((n / 8 + 255) / 256); };

    // hidden -> bf16
    cast_f32_bf16<<<nb8(2048L * 4096), 256, 0, stream>>>(hidden, hbf, 2048L * 4096);

    // q_a = hidden @ q_a_w^T, split-K=4 (grid 768 blocks), fp32 partials
    cast_f32_bf16<<<nb8(1536L * 4096), 256, 0, stream>>>(q_a_w, wbf, 1536L * 4096);
    gemm_bf16<0><<<dim3(12, 16, 4), 256, 0, stream>>>(hbf, wbf, parts, parts + 2048L * 1536,
                                                      2048, 1536, 1024, 4096, 4096);
    reduce_sum<<<2048, 256, 0, stream>>>(parts, qa_f32, 2048L * 1536, 4);
    rmsnorm_qa<<<2048, 256, 0, stream>>>(qa_f32, q_a_ln_w, qa_bf);

    // kv_a = hidden @ kv_a_w^T (N padded 640), split-K=8 (grid 640 blocks)
    cast_pad_kvaw<<<nb8(640L * 4096), 256, 0, stream>>>(kv_a_w, wbf);
    gemm_bf16<0><<<dim3(5, 16, 8), 256, 0, stream>>>(hbf, wbf, parts, parts + 2048L * 640,
                                                     2048, 640, 512, 4096, 4096);
    reduce_sum<<<1280, 256, 0, stream>>>(parts, kva_f32, 2048L * 640, 8);
    kv_norm_rope<<<2048, 256, 0, stream>>>(kva_f32, kv_a_ln_w, pos, cosT, sinT, ckv_bf, kpe_bf);

    // q = rms(q_a) @ q_b_w^T (bf16 out, grid 1536 blocks)
    cast_f32_bf16<<<nb8(12288L * 1536), 256, 0, stream>>>(q_b_w, wbf, 12288L * 1536);
    gemm_bf16<1><<<dim3(96, 16, 1), 256, 0, stream>>>(qa_bf, wbf, qbuf_bf, nullptr,
                                                      2048, 12288, 1536, 1536, 1536);
    qpe_rope_bf<<<32768, 256, 0, stream>>>(qbuf_bf, pos, cosT, sinT);

    // kvup = ckv @ kv_b_w^T (bf16 out, grid 2048 blocks)
    cast_f32_bf16<<<nb8(16384L * 512), 256, 0, stream>>>(kv_b_w, wbf, 16384L * 512);
    gemm_bf16<1><<<dim3(128, 16, 1), 256, 0, stream>>>(ckv_bf, wbf, kvup_bf, nullptr,
                                                       2048, 16384, 512, 512, 512);

    // flash attention, TQ=128
    attn_mfma<<<dim3(8, 64, 2), 512, 0, stream>>>(qbuf_bf, kvup_bf, kpe_bf, attno_bf);

    // out = attno @ o_w^T, split-K=2 (grid 1024 blocks): z0 -> out, z1 -> parts
    cast_f32_bf16<<<nb8(4096L * 8192), 256, 0, stream>>>(o_w, wbf, 4096L * 8192);
    gemm_bf16<0><<<dim3(32, 16, 2), 256, 0, stream>>>(attno_bf, wbf, out, parts,
                                                      2048, 4096, 4096, 8192, 8192);
    add_inplace<<<2048, 256, 0, stream>>>(out, parts, 2048L * 4096);
}